// Round 3
// baseline (233.252 us; speedup 1.0000x reference)
//
#include <hip/hip_runtime.h>
#include <hip/hip_fp16.h>
#include <stdint.h>

// out[b,o] = sum_{l,i} lookups[b,l]*values[b,i]*W[l,i,o] + sum_l lookups[b,l]*bias[l,o]
// GEMM M=65536, K=65 tiles of 64 (i-chunk outer, l inner; tile 64 = bias), N=256.
// fp16 MFMA; A = values staged per-chunk (unscaled), lookup scale applied in-reg.

#define B_TOK 65536
#define L_DIM 16
#define I_DIM 256
#define O_DIM 256
#define BM    256
#define THREADS 512

// LDS layout (single block, 116KB):
//   [0,32768)      B buf0   (pre-swizzled in global, linear gload_lds)
//   [32768,65536)  B buf1
//   [65536,98304)  A_chunk  [256 rows][64 kk] fp16, XOR-swizzled byte^((row&7)<<4)
//   [98304,118784) lookups  [256 rows][stride 20] f32
#define AOFF  65536
#define LKOFF 98304
#define LKS   20

typedef __attribute__((ext_vector_type(8))) _Float16 f16x8;
typedef __attribute__((ext_vector_type(4))) float f32x4;
typedef __attribute__((address_space(3))) void      lds_void_t;
typedef const __attribute__((address_space(1))) void gbl_void_t;

static __device__ __forceinline__ f16x8 scale8(f16x8 a, __half2 s) {
    union { f16x8 v; __half2 h[4]; } u; u.v = a;
#pragma unroll
    for (int q = 0; q < 4; ++q) u.h[q] = __hmul2(u.h[q], s);
    return u.v;
}

// ---------------------------------------------------------------------------
// prep_w: Wst = 65 tiles x 32KB fp16, [o][kk] (B-transposed), pre-swizzled:
// 16B chunk at position cp holds kk-group c = cp ^ (o&7).
// grid (65, 8) x 256 threads; 8 strided loads + 1 16B store per thread.
// ---------------------------------------------------------------------------
__global__ void prep_w(const float* __restrict__ W, const float* __restrict__ bias,
                       unsigned short* __restrict__ ws) {
    const int t  = blockIdx.x;           // tile 0..64
    const int o  = blockIdx.y * 32 + (threadIdx.x & 31);
    const int cp = threadIdx.x >> 5;     // chunk position after swizzle
    const int c  = cp ^ (o & 7);         // source kk-group (kk = c*8..c*8+7)
    uint32_t p[4];
    if (t < 64) {
        const int l = t & 15, ibase = (t >> 4) * 64;
        const float* src = W + ((size_t)l * I_DIM + ibase + c * 8) * O_DIM + o;
#pragma unroll
        for (int jp = 0; jp < 4; ++jp) {
            float a = src[(size_t)(2 * jp) * O_DIM];
            float b = src[(size_t)(2 * jp + 1) * O_DIM];
            p[jp] = __builtin_bit_cast(uint32_t, __floats2half2_rn(a, b));
        }
    } else if (c < 2) {                  // bias tile: kk<16 = bias, rest 0
#pragma unroll
        for (int jp = 0; jp < 4; ++jp) {
            int kk = c * 8 + 2 * jp;
            float a = bias[(size_t)kk * O_DIM + o];
            float b = bias[(size_t)(kk + 1) * O_DIM + o];
            p[jp] = __builtin_bit_cast(uint32_t, __floats2half2_rn(a, b));
        }
    } else {
        p[0] = p[1] = p[2] = p[3] = 0u;
    }
    uint4 q = {p[0], p[1], p[2], p[3]};
    *(uint4*)((char*)ws + (size_t)t * 32768 + o * 128 + cp * 16) = q;
}

// ---------------------------------------------------------------------------
__launch_bounds__(THREADS, 2)
__global__ void md_gemm(const float* __restrict__ lookups,        // [B][16]
                        const float* __restrict__ values,         // [B][256]
                        const unsigned short* __restrict__ Wst,   // [65][16384]
                        float* __restrict__ out) {                // [B][256]
    __shared__ char smem[118784];

    const int tid  = threadIdx.x;
    const int wid  = tid >> 6;
    const int lane = tid & 63;
    const int row0 = blockIdx.x * BM;

    // staging ownership: row r (0..255), half h (32 kk / 8 lookups)
    const int r = tid >> 1;
    const int h = tid & 1;

    // compute coords: 8 waves = 2M x 4N, wave tile 128x64
    const int wm   = wid >> 2;
    const int wn   = wid & 3;
    const int arow = wm * 128 + (lane & 15);
    const int bcol = wn * 64  + (lane & 15);
    const int kkl  = (lane >> 4) * 8;      // k-offset within tile (x2 bytes)

    f32x4 acc[8][4];
#pragma unroll
    for (int m = 0; m < 8; ++m)
#pragma unroll
        for (int n = 0; n < 4; ++n) acc[m][n] = (f32x4){0.f, 0.f, 0.f, 0.f};

    auto stageB = [&](int kt, int nb) {
        const char* src = (const char*)Wst + (size_t)kt * 32768 + wid * 1024 + lane * 16;
        char* dst = smem + nb * 32768 + wid * 1024;   // wave-uniform base (+lane*16 by HW)
#pragma unroll
        for (int s = 0; s < 4; ++s)
            __builtin_amdgcn_global_load_lds((gbl_void_t*)(src + s * 8192),
                                             (lds_void_t*)(dst + s * 8192), 16, 0, 0);
    };

    // ---- prologue: lookups -> LDS (padded), B(0) -> buf0 ----
    {
        const float4* lp = (const float4*)(lookups + (size_t)(row0 + r) * L_DIM + h * 8);
        float4 f0 = lp[0], f1 = lp[1];
        float* dst = (float*)(smem + LKOFF) + r * LKS + h * 8;
        *(float4*)dst = f0;
        *(float4*)(dst + 4) = f1;
    }
    stageB(0, 0);

    const float* lkp = (const float*)(smem + LKOFF);

    for (int cc = 0; cc < 4; ++cc) {
        // ---- stage A chunk (unscaled values, fp16, XOR-swizzled) ----
        {
            const float4* vp = (const float4*)(values + (size_t)(row0 + r) * I_DIM
                                               + cc * 64 + h * 32);
            uint32_t p[16];
#pragma unroll
            for (int j = 0; j < 8; ++j) {
                float4 f = vp[j];
                p[2 * j]     = __builtin_bit_cast(uint32_t, __floats2half2_rn(f.x, f.y));
                p[2 * j + 1] = __builtin_bit_cast(uint32_t, __floats2half2_rn(f.z, f.w));
            }
            char* ab = smem + AOFF;
#pragma unroll
            for (int w = 0; w < 4; ++w) {
                uint4 q = {p[4 * w], p[4 * w + 1], p[4 * w + 2], p[4 * w + 3]};
                *(uint4*)(ab + ((r * 128 + h * 64 + w * 16) ^ ((r & 7) << 4))) = q;
            }
        }
        __syncthreads();   // full drain: values + pending B loads + A ds_writes

        // ---- ks0 A-fragments resident for the whole chunk ----
        f16x8 afk0[8];
#pragma unroll
        for (int mt = 0; mt < 8; ++mt) {
            int row = arow + mt * 16;
            afk0[mt] = *(f16x8*)(smem + AOFF + ((row * 128 + kkl * 2) ^ ((row & 7) << 4)));
        }

        for (int l = 0; l < 16; ++l) {
            const int kt = cc * 16 + l;
            if (l != 0) {
                // B(kt) was issued at end of previous iter; its latency is hidden
                // under that iter's MFMAs. Fused wait+barrier, memory-fenced.
                asm volatile("s_waitcnt vmcnt(0)\n\ts_barrier" ::: "memory");
            }
            // per-(row,l) lookup scales from LDS (conflict-free, stride 20)
            __half2 lk2[8];
#pragma unroll
            for (int mt = 0; mt < 8; ++mt)
                lk2[mt] = __float2half2_rn(lkp[(arow + mt * 16) * LKS + l]);

            char* bbase = smem + (kt & 1) * 32768;
            // ---- ks = 0 (A resident) ----
            f16x8 bfr[4];
#pragma unroll
            for (int nt = 0; nt < 4; ++nt) {
                int o = bcol + nt * 16;
                bfr[nt] = *(f16x8*)(bbase + ((o * 128 + kkl * 2) ^ ((o & 7) << 4)));
            }
#pragma unroll
            for (int mt = 0; mt < 8; ++mt) {
                f16x8 a = scale8(afk0[mt], lk2[mt]);
#pragma unroll
                for (int nt = 0; nt < 4; ++nt)
                    acc[mt][nt] = __builtin_amdgcn_mfma_f32_16x16x32_f16(
                        a, bfr[nt], acc[mt][nt], 0, 0, 0);
            }
            // ---- ks = 1 (A streamed from LDS) ----
#pragma unroll
            for (int nt = 0; nt < 4; ++nt) {
                int o = bcol + nt * 16;
                bfr[nt] = *(f16x8*)(bbase + ((o * 128 + 64 + kkl * 2) ^ ((o & 7) << 4)));
            }
#pragma unroll
            for (int mt = 0; mt < 8; ++mt) {
                int row = arow + mt * 16;
                f16x8 a1 = *(f16x8*)(smem + AOFF
                                     + ((row * 128 + 64 + kkl * 2) ^ ((row & 7) << 4)));
                a1 = scale8(a1, lk2[mt]);
#pragma unroll
                for (int nt = 0; nt < 4; ++nt)
                    acc[mt][nt] = __builtin_amdgcn_mfma_f32_16x16x32_f16(
                        a1, bfr[nt], acc[mt][nt], 0, 0, 0);
            }
            // issue next B tile (kt+1 <= 64 always here); lands during next compute
            stageB(kt + 1, (kt + 1) & 1);
        }
        // protect A_chunk (and B buffers) before next chunk's stageA overwrites
        asm volatile("s_barrier" ::: "memory");
    }

    // ---- bias tile kt=64 (buf0; A = lookups in kk<16, zeros elsewhere) ----
    {
        uint32_t p[16];
#pragma unroll
        for (int j = 0; j < 16; ++j) p[j] = 0u;
        if (h == 0) {
            const float* lr = lkp + r * LKS;
#pragma unroll
            for (int j = 0; j < 8; ++j)
                p[j] = __builtin_bit_cast(uint32_t, __floats2half2_rn(lr[2 * j], lr[2 * j + 1]));
        }
        char* ab = smem + AOFF;
#pragma unroll
        for (int w = 0; w < 4; ++w) {
            uint4 q = {p[4 * w], p[4 * w + 1], p[4 * w + 2], p[4 * w + 3]};
            *(uint4*)(ab + ((r * 128 + h * 64 + w * 16) ^ ((r & 7) << 4))) = q;
        }
    }
    __syncthreads();   // drains B(64) gloads + A ds_writes
    {
        f16x8 bfr[4];
#pragma unroll
        for (int nt = 0; nt < 4; ++nt) {
            int o = bcol + nt * 16;
            bfr[nt] = *(f16x8*)(smem + ((o * 128 + kkl * 2) ^ ((o & 7) << 4)));
        }
#pragma unroll
        for (int mt = 0; mt < 8; ++mt) {
            int row = arow + mt * 16;
            f16x8 a0 = *(f16x8*)(smem + AOFF + ((row * 128 + kkl * 2) ^ ((row & 7) << 4)));
#pragma unroll
            for (int nt = 0; nt < 4; ++nt)
                acc[mt][nt] = __builtin_amdgcn_mfma_f32_16x16x32_f16(
                    a0, bfr[nt], acc[mt][nt], 0, 0, 0);
        }
    }

    // ---- epilogue: C/D layout col=lane&15, row=(lane>>4)*4+j ----
    const int orow = row0 + wm * 128 + (lane >> 4) * 4;
    const int ocol = wn * 64 + (lane & 15);
#pragma unroll
    for (int mt = 0; mt < 8; ++mt)
#pragma unroll
        for (int nt = 0; nt < 4; ++nt) {
#pragma unroll
            for (int j = 0; j < 4; ++j)
                out[(size_t)(orow + mt * 16 + j) * O_DIM + ocol + nt * 16] = acc[mt][nt][j];
        }
}

extern "C" void kernel_launch(void* const* d_in, const int* in_sizes, int n_in,
                              void* d_out, int out_size, void* d_ws, size_t ws_size,
                              hipStream_t stream) {
    const float* lookups = (const float*)d_in[0];
    const float* values  = (const float*)d_in[1];
    const float* W       = (const float*)d_in[2];
    const float* bias    = (const float*)d_in[3];
    unsigned short* Wst  = (unsigned short*)d_ws;   // 65*32768 B = 2.08 MB

    prep_w<<<dim3(65, 8), dim3(256), 0, stream>>>(W, bias, Wst);
    md_gemm<<<dim3(B_TOK / BM), dim3(THREADS), 0, stream>>>(lookups, values, Wst,
                                                            (float*)d_out);
}